// Round 4
// baseline (331.990 us; speedup 1.0000x reference)
//
#include <hip/hip_runtime.h>
#include <math.h>

// OFPenalty: power-iteration eigen-penalty on AAT = W W^T per batch, never
// materializing AAT. Round 6: max-TLP one-shot blocks.
//  - R3 (register streaming, NSPLIT=7) got k_step 52->~34us, but only 448
//    blocks (1.75 waves/SIMD) and a 7-chunk serial loop per block.
//  - Now: NSPLIT=49, one 32KB chunk per block, no loop, no double buffer.
//    3136 blocks, ~4 blocks/CU resident, 12 queued: latency hidden by TLP.
//  - normalize hoisted to k_norm (dense normalized x per step); k_step blocks
//    just stage 2KB of x-hat. k_mid consumes dense x1 + t5 partials and emits
//    normalized y-hat. k_step never reduces across blocks.
//  - k_repack: 8-row blocks (25KB LDS, 6 blocks/CU, 4096 blocks) vs 16-row
//    (50KB, 3/CU): double the occupancy to overlap load/store convoys.
// A: (64, 512, 28, 28) fp32 -> W: (64, 512, 784). x0: (64, 512, 1).

#define BB 64
#define CC 512
#define DD 784
#define NCH 49          // one 16-col chunk per block; 4 f4-quads per chunk
#define QTOT 196        // f4 columns
#define F4PR 196        // float4 per row of A
#define BF4 100352      // float4 per batch matrix (512*784/4)
#define FEPS 1e-12f

__device__ __forceinline__ void gload16(const float4* gp, float4* lp) {
    __builtin_amdgcn_global_load_lds(
        (const __attribute__((address_space(1))) void*)gp,
        (__attribute__((address_space(3))) void*)lp, 16, 0, 0);
}

__device__ __forceinline__ float blk_reduce(float s, float* red) {
    for (int off = 32; off; off >>= 1) s += __shfl_down(s, off, 64);
    int w = threadIdx.x >> 6;
    if ((threadIdx.x & 63) == 0) red[w] = s;
    __syncthreads();
    float t = red[0] + red[1] + red[2] + red[3];
    __syncthreads();                       // allow red[] reuse by caller
    return t;
}

// Repack A[b][c][d] -> T2[b][chq][c] (f4-column-major), chq = d>>2 in 0..195.
// Block = 8 rows x all d. Stage rows in LDS (25 KB) via global_load_lds, then
// write 196 segments of 8 f4 = 128 B (128B-aligned full lines).
__global__ __launch_bounds__(256, 6)
void k_repack(const float* __restrict__ A, float* __restrict__ T) {
    __shared__ float4 lds4[8 * F4PR];      // 1568 f4 = 25088 B
    const int tid = threadIdx.x, lane = tid & 63, w = tid >> 6;
    const int b = blockIdx.y, R0 = blockIdx.x * 8;
    const float4* src4 = (const float4*)A + ((size_t)b * CC + R0) * F4PR;
#pragma unroll
    for (int i = 0; i < 6; i++)
        gload16(src4 + i * 256 + w * 64 + lane, lds4 + i * 256 + w * 64);
    if (w == 0 && lane < 32) gload16(src4 + 1536 + lane, lds4 + 1536);
    __syncthreads();                        // drains vmcnt before barrier
    float4* dst4 = (float4*)T + (size_t)b * BF4;
#pragma unroll
    for (int j = 0; j < 7; j++) {
        int idx = j * 256 + tid;
        if (idx < 8 * F4PR) {
            int chq = idx >> 3, i = idx & 7;
            dst4[(size_t)chq * CC + R0 + i] = lds4[i * F4PR + chq];
        }
    }
}

// out[b][c] = normalize over c of (sum_p in[b][p][c]); nparts = 1 or NCH.
__global__ void k_norm(const float* __restrict__ in, const int nparts,
                       float* __restrict__ out) {
    __shared__ float red[4];
    int b = blockIdx.x;
    const float* ip = in + (size_t)b * nparts * CC;
    float v0 = 0.f, v1 = 0.f;
    for (int p = 0; p < nparts; p++) {
        v0 += ip[p * CC + threadIdx.x];
        v1 += ip[p * CC + threadIdx.x + 256];
    }
    float ss = blk_reduce(v0 * v0 + v1 * v1, red);
    float rn = 1.0f / fmaxf(sqrtf(ss), FEPS);
    float* op = out + (size_t)b * CC;
    op[threadIdx.x] = v0 * rn;
    op[threadIdx.x + 256] = v1 * rn;
}

// vout[b][s][c] = partial of (AAT_b * xhat[b])_c over chunk s (16 cols).
// xhat is DENSE, already normalized. Wave w owns f4-quad s*4+w; lane owns
// rows c = lane + 64k. One shot: 8 loads -> u-FMA -> butterfly -> v -> store.
template <bool RP>
__global__ __launch_bounds__(256, 4)
void k_step(const float* __restrict__ M, const float* __restrict__ xhat,
            float* __restrict__ vout) {
    __shared__ float xs[CC];
    __shared__ float vws[4][CC];

    const int tid = threadIdx.x;
    const int b = blockIdx.y, s = blockIdx.x;
    const int lane = tid & 63, w = tid >> 6;
    const int chq = s * 4 + w;
    const float4* Mb = (const float4*)M + (size_t)b * BF4;

    // issue the 8 wave-contiguous loads first (8 KB per wave)
    float4 a[8];
    if (RP) {
        const float4* g = Mb + (size_t)chq * CC + lane;
#pragma unroll
        for (int k = 0; k < 8; k++) a[k] = g[64 * k];
    } else {
        const float4* g = Mb + (size_t)lane * F4PR + chq;
#pragma unroll
        for (int k = 0; k < 8; k++) a[k] = g[(size_t)64 * k * F4PR];
    }

    // stage x-hat (dense, normalized)
    const float* xp = xhat + (size_t)b * CC;
    xs[tid] = xp[tid];
    xs[tid + 256] = xp[tid + 256];
    __syncthreads();
    float xk[8];
#pragma unroll
    for (int k = 0; k < 8; k++) xk[k] = xs[lane + 64 * k];

    // u-phase: u4 = sum_c A[c][quad] * xhat[c]
    float4 ua = make_float4(0.f, 0.f, 0.f, 0.f);
#pragma unroll
    for (int k = 0; k < 8; k++) {
        ua.x += a[k].x * xk[k]; ua.y += a[k].y * xk[k];
        ua.z += a[k].z * xk[k]; ua.w += a[k].w * xk[k];
    }
#pragma unroll
    for (int off = 1; off < 64; off <<= 1) {
        ua.x += __shfl_xor(ua.x, off, 64);
        ua.y += __shfl_xor(ua.y, off, 64);
        ua.z += __shfl_xor(ua.z, off, 64);
        ua.w += __shfl_xor(ua.w, off, 64);
    }

    // v-phase: vk[k] = A[c][quad] . u4
    float vk[8];
#pragma unroll
    for (int k = 0; k < 8; k++)
        vk[k] = a[k].x * ua.x + a[k].y * ua.y + a[k].z * ua.z + a[k].w * ua.w;

    // cross-wave quad sum
#pragma unroll
    for (int k = 0; k < 8; k++) vws[w][lane + 64 * k] = vk[k];
    __syncthreads();
    float* vp = vout + ((size_t)b * NCH + s) * CC;
    vp[tid]       = vws[0][tid] + vws[1][tid] + vws[2][tid] + vws[3][tid];
    vp[tid + 256] = vws[0][tid + 256] + vws[1][tid + 256] +
                    vws[2][tid + 256] + vws[3][tid + 256];
}

// inputs: x1 dense normalized, P = t5 partials (NCH). Outputs largest and
// yhat = normalize(t5 - largest*x1).
__global__ void k_mid(const float* __restrict__ x1, const float* __restrict__ P,
                      float* __restrict__ acc, float* __restrict__ yhat) {
    __shared__ float red[4];
    int b = blockIdx.x;
    const float* pp = P + (size_t)b * NCH * CC;
    float m0 = 0.f, m1 = 0.f;
    for (int p = 0; p < NCH; p++) {
        m0 += pp[p * CC + threadIdx.x];
        m1 += pp[p * CC + threadIdx.x + 256];
    }
    const float* xp = x1 + (size_t)b * CC;
    float x10 = xp[threadIdx.x], x11 = xp[threadIdx.x + 256];
    float num = blk_reduce(m0 * x10 + m1 * x11, red);
    float den = blk_reduce(x10 * x10 + x11 * x11, red);
    float largest = num / den;
    float y0 = m0 - largest * x10, y1 = m1 - largest * x11;
    float ssy = blk_reduce(y0 * y0 + y1 * y1, red);
    float rn = 1.0f / fmaxf(sqrtf(ssy), FEPS);
    float* yp = yhat + (size_t)b * CC;
    yp[threadIdx.x] = y0 * rn;
    yp[threadIdx.x + 256] = y1 * rn;
    if (threadIdx.x == 0) acc[b * 8 + 0] = largest;
}

// P = w partials (NCH), yhat dense (unit). dotwx = <w, x2>, den2 = <x2,x2>,
// x2 = yhat/||yhat|| (idempotent renormalize kept for exactness).
__global__ void k_fin2(const float* __restrict__ P, const float* __restrict__ yhat,
                       float* __restrict__ acc) {
    __shared__ float red[4];
    int b = blockIdx.x;
    const float* pp = P + (size_t)b * NCH * CC;
    float w0 = 0.f, w1 = 0.f;
    for (int p = 0; p < NCH; p++) {
        w0 += pp[p * CC + threadIdx.x];
        w1 += pp[p * CC + threadIdx.x + 256];
    }
    const float* yp = yhat + (size_t)b * CC;
    float y0 = yp[threadIdx.x], y1 = yp[threadIdx.x + 256];
    float ssy = blk_reduce(y0 * y0 + y1 * y1, red);
    float rn = 1.0f / fmaxf(sqrtf(ssy), FEPS);
    float x20 = y0 * rn, x21 = y1 * rn;
    float dotwx = blk_reduce(w0 * x20 + w1 * x21, red);
    float den2 = blk_reduce(x20 * x20 + x21 * x21, red);
    if (threadIdx.x == 0) { acc[b * 8 + 1] = dotwx; acc[b * 8 + 2] = den2; }
}

__global__ void k_out(const float* __restrict__ acc, float* __restrict__ out) {
    int b = threadIdx.x;                   // 64 threads = 1 wave
    float largest = acc[b * 8 + 0];
    float dotwx   = acc[b * 8 + 1];
    float den2    = acc[b * 8 + 2];
    float tmp = (dotwx - largest * den2) / den2;
    float smallest = tmp + largest;
    float r = largest / smallest - 1.0f;
    float pen = r * r;                     // BETA = 1
    for (int off = 32; off; off >>= 1) pen += __shfl_down(pen, off, 64);
    if (b == 0) out[0] = pen / (float)BB;
}

extern "C" void kernel_launch(void* const* d_in, const int* in_sizes, int n_in,
                              void* d_out, int out_size, void* d_ws, size_t ws_size,
                              hipStream_t stream) {
    const float* A  = (const float*)d_in[0];
    const float* x0 = (const float*)d_in[1];
    float* out = (float*)d_out;
    float* ws = (float*)d_ws;

    float* acc = ws;                          // 512 floats (64 x 8)
    float* X   = ws + 512;                    // BB*CC dense x-hat
    float* Y   = X + BB * CC;                 // BB*CC dense y-hat
    float* P   = Y + BB * CC;                 // BB*NCH*CC partials (6.4 MB)
    float* T   = P + (size_t)BB * NCH * CC;   // BB*CC*DD = 102.8 MB
    const size_t need =
        ((size_t)512 + 2 * BB * CC + (size_t)BB * NCH * CC +
         (size_t)BB * CC * DD) * sizeof(float);

    dim3 gS(NCH, BB);
    if (ws_size >= need) {
        k_repack<<<dim3(CC / 8, BB), 256, 0, stream>>>(A, T);
        k_norm<<<BB, 256, 0, stream>>>(x0, 1, X);
        k_step<true><<<gS, 256, 0, stream>>>(T, X, P);   // t1 partials
        k_norm<<<BB, 256, 0, stream>>>(P, NCH, X);
        k_step<true><<<gS, 256, 0, stream>>>(T, X, P);   // t2
        k_norm<<<BB, 256, 0, stream>>>(P, NCH, X);
        k_step<true><<<gS, 256, 0, stream>>>(T, X, P);   // t3
        k_norm<<<BB, 256, 0, stream>>>(P, NCH, X);
        k_step<true><<<gS, 256, 0, stream>>>(T, X, P);   // t4
        k_norm<<<BB, 256, 0, stream>>>(P, NCH, X);       // X = x1
        k_step<true><<<gS, 256, 0, stream>>>(T, X, P);   // t5 = Mx
        k_mid<<<BB, 256, 0, stream>>>(X, P, acc, Y);     // largest, yhat
        k_step<true><<<gS, 256, 0, stream>>>(T, Y, P);   // w
        k_fin2<<<BB, 256, 0, stream>>>(P, Y, acc);
    } else {
        k_norm<<<BB, 256, 0, stream>>>(x0, 1, X);
        k_step<false><<<gS, 256, 0, stream>>>(A, X, P);
        k_norm<<<BB, 256, 0, stream>>>(P, NCH, X);
        k_step<false><<<gS, 256, 0, stream>>>(A, X, P);
        k_norm<<<BB, 256, 0, stream>>>(P, NCH, X);
        k_step<false><<<gS, 256, 0, stream>>>(A, X, P);
        k_norm<<<BB, 256, 0, stream>>>(P, NCH, X);
        k_step<false><<<gS, 256, 0, stream>>>(A, X, P);
        k_norm<<<BB, 256, 0, stream>>>(P, NCH, X);
        k_step<false><<<gS, 256, 0, stream>>>(A, X, P);
        k_mid<<<BB, 256, 0, stream>>>(X, P, acc, Y);
        k_step<false><<<gS, 256, 0, stream>>>(A, Y, P);
        k_fin2<<<BB, 256, 0, stream>>>(P, Y, acc);
    }
    k_out<<<1, 64, 0, stream>>>(acc, out);
}